// Round 6
// baseline (164.001 us; speedup 1.0000x reference)
//
#include <hip/hip_runtime.h>

#define LQ 768
#define DIN 256
#define DB 128
#define NH 8
#define DH 32

// ws float offsets
#define OFF_QB 0
#define OFF_KT (LQ*DIN)          // kT[DIN][LQ]  (transposed, pre-scaled K)
#define OFF_VB (2*LQ*DIN)
#define OFF_GB (3*LQ*DIN)
#define OFF_W2 (4*LQ*DIN)
#define OFF_SC (OFF_W2 + DB*NH)
#define OFF_LG (OFF_SC + 16)

// ---------------------------------------------------------------------------
// Setup: W2[d][h] = lbw[d]*Wb[d][h]; S[h] = sum_d W2; C[h] = sum_d lbb[d]*Wb.
// ---------------------------------------------------------------------------
__global__ __launch_bounds__(128) void setup_kernel(
    const float* __restrict__ lbw, const float* __restrict__ lbb,
    const float* __restrict__ Wb, float* __restrict__ W2, float* __restrict__ SC)
{
    const int d = threadIdx.x;          // 0..127
    const int lane = d & 63, wv = d >> 6;
    float w = lbw[d], b = lbb[d];
    float pS[NH], pC[NH];
    #pragma unroll
    for (int h = 0; h < NH; h++) {
        float wb = Wb[d*NH + h];
        float w2 = w * wb;
        W2[d*NH + h] = w2;
        pS[h] = w2;
        pC[h] = b * wb;
    }
    #pragma unroll
    for (int m = 1; m <= 32; m <<= 1) {
        #pragma unroll
        for (int h = 0; h < NH; h++) { pS[h] += __shfl_xor(pS[h], m); pC[h] += __shfl_xor(pC[h], m); }
    }
    __shared__ float red[2][16];
    if (lane == 0) {
        #pragma unroll
        for (int h = 0; h < NH; h++) { red[wv][h] = pS[h]; red[wv][NH+h] = pC[h]; }
    }
    __syncthreads();
    if (d < 16) SC[d] = red[0][d] + red[1][d];
}

// ---------------------------------------------------------------------------
// Proj: LN(x) + Q/K/V/gate. 4 rows/block. K written TRANSPOSED + pre-scaled.
// ---------------------------------------------------------------------------
__global__ __launch_bounds__(256) void proj_kernel(
    const float* __restrict__ x, const float* __restrict__ lnw, const float* __restrict__ lnb,
    const float* __restrict__ Wq, const float* __restrict__ Wk, const float* __restrict__ Wv,
    const float* __restrict__ Wg, const float* __restrict__ bg,
    float* __restrict__ qb, float* __restrict__ kT, float* __restrict__ vb, float* __restrict__ gb)
{
    const int tid = threadIdx.x;
    const int lane = tid & 63, rr = tid >> 6;
    const int row = blockIdx.x * 4 + rr;
    __shared__ float xn[4][DIN];

    float4 xv = ((const float4*)x)[row * (DIN/4) + lane];
    float s  = xv.x + xv.y + xv.z + xv.w;
    float ss = xv.x*xv.x + xv.y*xv.y + xv.z*xv.z + xv.w*xv.w;
    #pragma unroll
    for (int m = 1; m <= 32; m <<= 1) { s += __shfl_xor(s, m); ss += __shfl_xor(ss, m); }
    float mu  = s * (1.0f/DIN);
    float inv = rsqrtf(ss * (1.0f/DIN) - mu*mu + 1e-5f);
    float4 wv4 = ((const float4*)lnw)[lane];
    float4 bv4 = ((const float4*)lnb)[lane];
    float4 r4;
    r4.x = (xv.x - mu)*inv*wv4.x + bv4.x;
    r4.y = (xv.y - mu)*inv*wv4.y + bv4.y;
    r4.z = (xv.z - mu)*inv*wv4.z + bv4.z;
    r4.w = (xv.w - mu)*inv*wv4.w + bv4.w;
    *((float4*)&xn[rr][lane*4]) = r4;
    __syncthreads();

    const int col = tid;
    float aq[4] = {0,0,0,0}, ak[4] = {0,0,0,0}, av[4] = {0,0,0,0}, ag[4] = {0,0,0,0};
    for (int i4 = 0; i4 < DIN/4; i4++) {
        float4 x0 = *((const float4*)&xn[0][i4*4]);
        float4 x1 = *((const float4*)&xn[1][i4*4]);
        float4 x2 = *((const float4*)&xn[2][i4*4]);
        float4 x3 = *((const float4*)&xn[3][i4*4]);
        const float* p0 = (const float*)&x0;
        const float* p1 = (const float*)&x1;
        const float* p2 = (const float*)&x2;
        const float* p3 = (const float*)&x3;
        #pragma unroll
        for (int e = 0; e < 4; e++) {
            const int i = i4*4 + e;
            float wq = Wq[i*DIN + col], wk = Wk[i*DIN + col];
            float wvv = Wv[i*DIN + col], wg = Wg[i*DIN + col];
            aq[0] = fmaf(p0[e], wq, aq[0]); aq[1] = fmaf(p1[e], wq, aq[1]);
            aq[2] = fmaf(p2[e], wq, aq[2]); aq[3] = fmaf(p3[e], wq, aq[3]);
            ak[0] = fmaf(p0[e], wk, ak[0]); ak[1] = fmaf(p1[e], wk, ak[1]);
            ak[2] = fmaf(p2[e], wk, ak[2]); ak[3] = fmaf(p3[e], wk, ak[3]);
            av[0] = fmaf(p0[e], wvv, av[0]); av[1] = fmaf(p1[e], wvv, av[1]);
            av[2] = fmaf(p2[e], wvv, av[2]); av[3] = fmaf(p3[e], wvv, av[3]);
            ag[0] = fmaf(p0[e], wg, ag[0]); ag[1] = fmaf(p1[e], wg, ag[1]);
            ag[2] = fmaf(p2[e], wg, ag[2]); ag[3] = fmaf(p3[e], wg, ag[3]);
        }
    }
    const float kscale = 0.17677669529663687f;  // 1/sqrt(DH)
    float bgv = bg[col];
    #pragma unroll
    for (int r = 0; r < 4; r++) {
        const int orow = blockIdx.x*4 + r;
        qb[orow*DIN + col] = aq[r];
        vb[orow*DIN + col] = av[r];
        gb[orow*DIN + col] = 1.0f/(1.0f + __expf(-(ag[r] + bgv)));
    }
    *((float4*)&kT[col*LQ + blockIdx.x*4]) =
        make_float4(ak[0]*kscale, ak[1]*kscale, ak[2]*kscale, ak[3]*kscale);
}

// ---------------------------------------------------------------------------
// Bias stream v3 (column-scan): lane = key, d is a wave-uniform serial loop.
//  - W2 rows come in via s_load (SGPR broadcast) -> ZERO LDS traffic for W2.
//  - No cross-lane reduction at all (full key per lane).
//  - LDS tile padded to 129 words/row: column read banks (lane+d)&31 -> free.
//  - Reg-staged async pipeline (T14): issue 32 dwordx4 for tile t+1, scan
//    tile t (hides HBM latency), auto-vmcnt, 128 ds_write_b32.
// Grid 512 x 128 (2 waves/block); wave = blockIdx.x*2+w handles 9 tiles of
// 64 keys x 128 dims (32KB). 9216 tiles total. Barrier-free.
// ---------------------------------------------------------------------------
__global__ __launch_bounds__(128) void bias_kernel(
    const float* __restrict__ bias, const float* __restrict__ W2g,
    const float* __restrict__ SCg, float* __restrict__ logits)
{
    __shared__ float tile[2][64 * 129];   // 66 KB/block -> 2 blocks/CU
    const int tid  = threadIdx.x;
    const int w    = tid >> 6;
    const int lane = tid & 63;
    const int wid  = blockIdx.x * 2 + w;

    float* tw = &tile[w][0];
    const int wbase = (lane >> 5) * 129 + (lane & 31) * 4;  // write base (floats)
    const int rbase = lane * 129;                           // read base (floats)

    float Sh[NH], Ch[NH];
    #pragma unroll
    for (int h = 0; h < NH; h++) { Sh[h] = SCg[h]; Ch[h] = SCg[NH + h]; }

    float4 v[32];

    const int tau0 = wid * 9;

    // ---- prologue: load + write tile tau0 ----
    {
        const int q  = tau0 / 12;
        const int kb = (tau0 % 12) * 64;
        const float4* gs = (const float4*)(bias + ((size_t)q * LQ + kb) * DB);
        #pragma unroll
        for (int c = 0; c < 32; c++) v[c] = gs[c * 64 + lane];
        #pragma unroll
        for (int c = 0; c < 32; c++) {
            tw[wbase + c*258 + 0] = v[c].x;
            tw[wbase + c*258 + 1] = v[c].y;
            tw[wbase + c*258 + 2] = v[c].z;
            tw[wbase + c*258 + 3] = v[c].w;
        }
    }

    for (int t = 0; t < 9; t++) {
        const int tau = tau0 + t;

        // issue prefetch loads for tile t+1 (land during the scan below)
        if (t + 1 < 9) {
            const int qn  = (tau + 1) / 12;
            const int kbn = ((tau + 1) % 12) * 64;
            const float4* gs = (const float4*)(bias + ((size_t)qn * LQ + kbn) * DB);
            #pragma unroll
            for (int c = 0; c < 32; c++) v[c] = gs[c * 64 + lane];
        }
        asm volatile("" ::: "memory");   // pin: loads issued before the scan

        // ---- scan tile t: per-lane full-key stats + 8-head projection ----
        float s = 0.f, ss = 0.f;
        float acc[NH] = {0,0,0,0,0,0,0,0};
        #pragma unroll 4
        for (int d = 0; d < DB; d++) {
            float xv = tw[rbase + d];                 // bank (lane+d)&31: free
            const float* wr = W2g + d * NH;           // uniform -> s_load
            s += xv; ss = fmaf(xv, xv, ss);
            #pragma unroll
            for (int h = 0; h < NH; h++) acc[h] = fmaf(xv, wr[h], acc[h]);
        }

        // ---- finalize + store logits for tile t ----
        {
            const int q  = tau / 12;
            const int kb = (tau % 12) * 64;
            float mu  = s * (1.0f/DB);
            float inv = rsqrtf(ss * (1.0f/DB) - mu*mu + 1e-5f);
            float lo[NH];
            #pragma unroll
            for (int h = 0; h < NH; h++)
                lo[h] = fmaf(inv, fmaf(-mu, Sh[h], acc[h]), Ch[h]);
            float4* dst = (float4*)(logits + ((size_t)q*LQ + kb + lane)*NH);
            dst[0] = make_float4(lo[0], lo[1], lo[2], lo[3]);
            dst[1] = make_float4(lo[4], lo[5], lo[6], lo[7]);
        }

        // ---- write tile t+1 into LDS (auto vmcnt on v[], WAR-safe: scan done) ----
        if (t + 1 < 9) {
            #pragma unroll
            for (int c = 0; c < 32; c++) {
                tw[wbase + c*258 + 0] = v[c].x;
                tw[wbase + c*258 + 1] = v[c].y;
                tw[wbase + c*258 + 2] = v[c].z;
                tw[wbase + c*258 + 3] = v[c].w;
            }
        }
    }
}

// ---------------------------------------------------------------------------
// Attn: logits -> pT[r][h][k] (transposed, padded 776), add qk from kT,
// softmax along contiguous rows (float4), PV with coalesced V reads,
// gate, Wo. 2 q-rows per block, grid 384.
// ---------------------------------------------------------------------------
__global__ __launch_bounds__(256) void attn_kernel(
    const float* __restrict__ logits, const float* __restrict__ qbuf,
    const float* __restrict__ kT, const float* __restrict__ vbuf,
    const float* __restrict__ gb, const float* __restrict__ Wo,
    const float* __restrict__ bo, float* __restrict__ out)
{
    const int tid = threadIdx.x;
    const int q0 = blockIdx.x * 2;
    __shared__ float pT[2][NH][776];
    __shared__ float ao[2][DIN];
    __shared__ float isum[2][NH];

    #pragma unroll
    for (int r = 0; r < 2; r++) {
        const float4* rp = (const float4*)(logits + (size_t)(q0 + r)*LQ*NH);
        #pragma unroll
        for (int ii = 0; ii < 6; ii++) {
            int jj = ii*256 + tid;
            float4 t = rp[jj];
            int k = jj >> 1, h0 = (jj & 1) << 2;
            pT[r][h0+0][k] = t.x; pT[r][h0+1][k] = t.y;
            pT[r][h0+2][k] = t.z; pT[r][h0+3][k] = t.w;
        }
    }
    __syncthreads();

    if (tid < 192) {
        const float* q0p = qbuf + (size_t)q0*DIN;
        const float* q1p = q0p + DIN;
        #pragma unroll
        for (int h = 0; h < NH; h++) {
            float a00=0,a01=0,a02=0,a03=0, a10=0,a11=0,a12=0,a13=0;
            #pragma unroll
            for (int dd = 0; dd < DH; dd++) {
                const int d = h*DH + dd;
                float4 kv = *(const float4*)(kT + (size_t)d*LQ + tid*4);
                float qa = q0p[d], qc = q1p[d];
                a00 = fmaf(qa, kv.x, a00); a01 = fmaf(qa, kv.y, a01);
                a02 = fmaf(qa, kv.z, a02); a03 = fmaf(qa, kv.w, a03);
                a10 = fmaf(qc, kv.x, a10); a11 = fmaf(qc, kv.y, a11);
                a12 = fmaf(qc, kv.z, a12); a13 = fmaf(qc, kv.w, a13);
            }
            float4 p0 = *(float4*)&pT[0][h][tid*4];
            p0.x += a00; p0.y += a01; p0.z += a02; p0.w += a03;
            *(float4*)&pT[0][h][tid*4] = p0;
            float4 p1 = *(float4*)&pT[1][h][tid*4];
            p1.x += a10; p1.y += a11; p1.z += a12; p1.w += a13;
            *(float4*)&pT[1][h][tid*4] = p1;
        }
    }
    __syncthreads();

    {
        const int r = tid >> 7, h = (tid >> 4) & 7, l = tid & 15;
        float4* row = (float4*)&pT[r][h][0];
        float m = -1e30f;
        for (int i = l; i < 192; i += 16) {
            float4 v = row[i];
            m = fmaxf(m, fmaxf(fmaxf(v.x, v.y), fmaxf(v.z, v.w)));
        }
        #pragma unroll
        for (int mm = 1; mm <= 8; mm <<= 1) m = fmaxf(m, __shfl_xor(m, mm));
        float sum = 0.f;
        for (int i = l; i < 192; i += 16) {
            float4 v = row[i];
            v.x = __expf(v.x - m); v.y = __expf(v.y - m);
            v.z = __expf(v.z - m); v.w = __expf(v.w - m);
            sum += v.x + v.y + v.z + v.w;
            row[i] = v;
        }
        #pragma unroll
        for (int mm = 1; mm <= 8; mm <<= 1) sum += __shfl_xor(sum, mm);
        if (l == 0) isum[r][h] = 1.0f / sum;
    }
    __syncthreads();

    {
        const int h = tid >> 5, d = tid & 31;
        const float* vp = vbuf + h*DH + d;
        const float4* p0r = (const float4*)&pT[0][h][0];
        const float4* p1r = (const float4*)&pT[1][h][0];
        float a0 = 0.f, a1 = 0.f;
        for (int k4 = 0; k4 < 192; k4++) {
            float4 p0 = p0r[k4], p1 = p1r[k4];
            float v0 = vp[(size_t)(k4*4+0)*DIN];
            float v1 = vp[(size_t)(k4*4+1)*DIN];
            float v2 = vp[(size_t)(k4*4+2)*DIN];
            float v3 = vp[(size_t)(k4*4+3)*DIN];
            a0 = fmaf(p0.x, v0, a0); a0 = fmaf(p0.y, v1, a0);
            a0 = fmaf(p0.z, v2, a0); a0 = fmaf(p0.w, v3, a0);
            a1 = fmaf(p1.x, v0, a1); a1 = fmaf(p1.y, v1, a1);
            a1 = fmaf(p1.z, v2, a1); a1 = fmaf(p1.w, v3, a1);
        }
        ao[0][tid] = a0 * isum[0][h] * gb[(q0+0)*DIN + tid];
        ao[1][tid] = a1 * isum[1][h] * gb[(q0+1)*DIN + tid];
    }
    __syncthreads();

    {
        const int col = tid;
        float o0 = bo[col], o1 = o0;
        for (int i = 0; i < DIN; i++) {
            float wv = Wo[i*DIN + col];
            o0 = fmaf(ao[0][i], wv, o0);
            o1 = fmaf(ao[1][i], wv, o1);
        }
        out[(q0+0)*DIN + col] = o0;
        out[(q0+1)*DIN + col] = o1;
    }
}

extern "C" void kernel_launch(void* const* d_in, const int* in_sizes, int n_in,
                              void* d_out, int out_size, void* d_ws, size_t ws_size,
                              hipStream_t stream) {
    const float* x    = (const float*)d_in[0];
    const float* bias = (const float*)d_in[1];
    const float* lnw  = (const float*)d_in[2];
    const float* lnb  = (const float*)d_in[3];
    const float* lbw  = (const float*)d_in[4];
    const float* lbb  = (const float*)d_in[5];
    const float* Wq   = (const float*)d_in[6];
    const float* Wk   = (const float*)d_in[7];
    const float* Wv   = (const float*)d_in[8];
    const float* Wb   = (const float*)d_in[9];
    const float* Wg   = (const float*)d_in[10];
    const float* bg   = (const float*)d_in[11];
    const float* Wo   = (const float*)d_in[12];
    const float* bo   = (const float*)d_in[13];

    float* ws = (float*)d_ws;
    float* qb = ws + OFF_QB;
    float* kT = ws + OFF_KT;
    float* vb = ws + OFF_VB;
    float* gb = ws + OFF_GB;
    float* W2 = ws + OFF_W2;
    float* SC = ws + OFF_SC;
    float* lg = ws + OFF_LG;

    setup_kernel<<<1, 128, 0, stream>>>(lbw, lbb, Wb, W2, SC);
    proj_kernel<<<LQ/4, 256, 0, stream>>>(x, lnw, lnb, Wq, Wk, Wv, Wg, bg, qb, kT, vb, gb);
    bias_kernel<<<512, 128, 0, stream>>>(bias, W2, SC, lg);
    attn_kernel<<<LQ/2, 256, 0, stream>>>(lg, qb, kT, vb, gb, Wo, bo, (float*)d_out);
}